// Round 14
// baseline (468.037 us; speedup 1.0000x reference)
//
#include <hip/hip_runtime.h>
#include <hip/hip_bf16.h>

// B=32, C=3, H=W=128, D=512, K=512, S=4, NPOS=32768
#define NPOS 32768
#define EPS_GAP 4e-3f
#define MAXSUS 4096

typedef __attribute__((ext_vector_type(8))) short short8;
typedef __attribute__((ext_vector_type(4))) float floatx4;

static __device__ __forceinline__ float bfu(unsigned short h) {
    return __uint_as_float(((unsigned int)h) << 16);
}
static __device__ __forceinline__ unsigned short f2bf(float f) {
    unsigned int u = __float_as_uint(f);
    u = (u + 0x7fffu + ((u >> 16) & 1u)) >> 16;   // RNE
    return (unsigned short)u;
}
static __device__ __forceinline__ float ldin(const void* p, size_t i, int flag) {
    return flag ? bfu(((const unsigned short*)p)[i]) : ((const float*)p)[i];
}

// ---------------------------------------------------------------------------
__global__ void k_init(int* __restrict__ scnt, int* __restrict__ nbad) {
    *scnt = 0; *nbad = 0;
}

// 64 blocks x 64 threads: block = column k; shuffle-reduce sumsq.
__global__ void k_sniff(const void* __restrict__ cb, int* __restrict__ nbad) {
    const unsigned short* u = (const unsigned short*)cb;
    const int k = blockIdx.x, t = threadIdx.x;
    float acc = 0.f;
    #pragma unroll
    for (int i = 0; i < 8; ++i) {
        float v = bfu(u[(size_t)(t + 64 * i) * 512 + k]);
        acc = fmaf(v, v, acc);
    }
    #pragma unroll
    for (int m = 1; m < 64; m <<= 1) acc += __shfl_xor(acc, m);
    if (t == 0 && !(acc >= 100.f && acc <= 2000.f)) atomicAdd(nbad, 1);
}

// ---------------------------------------------------------------------------
// FUSED prep (one launch, 292 blocks x 256):
//  [0,64):    codebook transpose tiles -> cbT fp32 [k][d], cbHT/cbLT bf16 [k][d]
//  [64,162):  canonW -> cWe, cbe (fp32)
//  [162,164): w2[k] = sum_d cb[d][k]^2 (double), raw reads
//  [164,292): udec -> U[k][48], raw reads of cb/Wd/bd
// ---------------------------------------------------------------------------
__global__ __launch_bounds__(256) void k_prep(
        const void* __restrict__ cb, const void* __restrict__ We,
        const void* __restrict__ be, const void* __restrict__ Wd,
        const void* __restrict__ bd, const int* __restrict__ nbadp,
        float* __restrict__ cWe, float* __restrict__ cbe,
        float* __restrict__ cbT, unsigned short* __restrict__ cbHT,
        unsigned short* __restrict__ cbLT, float* __restrict__ w2,
        double* __restrict__ w2d, float* __restrict__ U) {
    __shared__ float tile[64][65];
    const int flag = (*nbadp == 0);
    const int blk = blockIdx.x, t = threadIdx.x;

    if (blk < 64) {
        const int D0 = (blk & 7) * 64, K0 = (blk >> 3) * 64;
        for (int it = 0; it < 16; ++it) {
            int r = (t >> 6) + 4 * it, c = t & 63;
            tile[r][c] = ldin(cb, (size_t)(D0 + r) * 512 + K0 + c, flag);
        }
        __syncthreads();
        for (int it = 0; it < 16; ++it) {
            int r = (t >> 6) + 4 * it, c = t & 63;
            float v = tile[c][r];
            size_t o = (size_t)(K0 + r) * 512 + D0 + c;
            cbT[o] = v;
            unsigned short h = f2bf(v);
            cbHT[o] = h;
            cbLT[o] = f2bf(v - bfu(h));
        }
    } else if (blk < 162) {
        int e = (blk - 64) * 256 + t;
        if (e < 24576)      cWe[e]         = ldin(We, e, flag);
        else if (e < 25088) cbe[e - 24576] = ldin(be, e - 24576, flag);
    } else if (blk < 164) {
        int k = (blk - 162) * 256 + t;
        double acc = 0.0;
        for (int d = 0; d < 512; ++d) {
            double v = (double)ldin(cb, (size_t)d * 512 + k, flag);
            acc += v * v;
        }
        w2[k] = (float)acc;
        w2d[k] = acc;
    } else {
        const int k = (blk - 164) * 4 + (t >> 6);
        const int lane = t & 63;
        const int j = lane >> 2, dpart = lane & 3;
        const int u = (j >> 2) & 3, v = j & 3;
        int woff[3];
        #pragma unroll
        for (int m = 0; m < 3; ++m) woff[m] = m * 8192 + (3 - u) * 4 + (3 - v);
        float a0 = 0.f, a1 = 0.f, a2 = 0.f;
        for (int i = 0; i < 128; ++i) {
            int d = dpart * 128 + i;
            float cw = ldin(cb, (size_t)d * 512 + k, flag);
            a0 = fmaf(cw, ldin(Wd, woff[0] + d * 16, flag), a0);
            a1 = fmaf(cw, ldin(Wd, woff[1] + d * 16, flag), a1);
            a2 = fmaf(cw, ldin(Wd, woff[2] + d * 16, flag), a2);
        }
        a0 += __shfl_xor(a0, 1); a0 += __shfl_xor(a0, 2);
        a1 += __shfl_xor(a1, 1); a1 += __shfl_xor(a1, 2);
        a2 += __shfl_xor(a2, 1); a2 += __shfl_xor(a2, 2);
        if (dpart == 0) {
            U[k * 48 +  0 + j] = a0 + ldin(bd, 0, flag);
            U[k * 48 + 16 + j] = a1 + ldin(bd, 1, flag);
            U[k * 48 + 32 + j] = a2 + ldin(bd, 2, flag);
        }
    }
}

// ---------------------------------------------------------------------------
// k_main v6 helpers. 64 pos/block, 512 threads. z pair buffer = 5120 shorts:
//   H at [pos*40 + d], L at [2560 + pos*40 + d].
// ---------------------------------------------------------------------------
static __device__ __forceinline__ void conv_step(
        const float* __restrict__ patch, const float* __restrict__ cWe,
        const float* __restrict__ cbe, int dc, int t,
        unsigned short* __restrict__ zq) {
    const int cd = t & 31;          // d within chunk
    const int ps = (t >> 5) * 4;    // 16 groups x 4 positions
    const float4* wv = (const float4*)(cWe + (size_t)(dc + cd) * 48);
    const float bias = cbe[dc + cd];
    float za[4];
    #pragma unroll
    for (int p = 0; p < 4; ++p) za[p] = bias;
    #pragma unroll
    for (int q4 = 0; q4 < 12; ++q4) {
        float4 wq = wv[q4];
        #pragma unroll
        for (int p = 0; p < 4; ++p) {
            float4 v = ((const float4*)(patch + (ps + p) * 48))[q4];
            za[p] = fmaf(v.x, wq.x, za[p]);
            za[p] = fmaf(v.y, wq.y, za[p]);
            za[p] = fmaf(v.z, wq.z, za[p]);
            za[p] = fmaf(v.w, wq.w, za[p]);
        }
    }
    #pragma unroll
    for (int p = 0; p < 4; ++p) {
        float z = fmaxf(za[p], 0.f);
        unsigned short h = f2bf(z);
        zq[(ps + p) * 40 + cd] = h;
        zq[2560 + (ps + p) * 40 + cd] = f2bf(z - bfu(h));
    }
}

static __device__ __forceinline__ void mfma_step(
        const unsigned short* __restrict__ zq,
        const unsigned short* __restrict__ cbHT,
        const unsigned short* __restrict__ cbLT,
        int dcPrev, int mh, int nw, int quad, int lcol, int flag,
        floatx4 (&acc)[2][8]) {
    short8 aH[2], aL[2];
    #pragma unroll
    for (int mt = 0; mt < 2; ++mt) {
        int pos = (mh * 2 + mt) * 16 + lcol;
        aH[mt] = *(const short8*)(zq + pos * 40 + quad * 8);
        aL[mt] = *(const short8*)(zq + 2560 + pos * 40 + quad * 8);
    }
    #pragma unroll
    for (int j = 0; j < 8; ++j) {
        int code = (nw * 8 + j) * 16 + lcol;
        short8 bH = *(const short8*)(cbHT + (size_t)code * 512 + dcPrev + quad * 8);
        #pragma unroll
        for (int mt = 0; mt < 2; ++mt) {
            acc[mt][j] = __builtin_amdgcn_mfma_f32_16x16x32_bf16(aH[mt], bH, acc[mt][j], 0, 0, 0);
            acc[mt][j] = __builtin_amdgcn_mfma_f32_16x16x32_bf16(aL[mt], bH, acc[mt][j], 0, 0, 0);
        }
    }
    if (!flag) {   // fp32 inputs: third term zh*cbL
        #pragma unroll
        for (int j = 0; j < 8; ++j) {
            int code = (nw * 8 + j) * 16 + lcol;
            short8 bL = *(const short8*)(cbLT + (size_t)code * 512 + dcPrev + quad * 8);
            #pragma unroll
            for (int mt = 0; mt < 2; ++mt)
                acc[mt][j] = __builtin_amdgcn_mfma_f32_16x16x32_bf16(aH[mt], bL, acc[mt][j], 0, 0, 0);
        }
    }
}

// Coalesced out_z: one wave = 64 consecutive positions of one d-row = 256 B line.
static __device__ __forceinline__ void outz_step(
        const unsigned short* __restrict__ zq, int dcPrev, int t,
        int b, int SP0, float* __restrict__ out_z) {
    const int col = t & 63;        // position
    const int wv = t >> 6;         // 8 waves x 4 d-rows
    ushort4 h = *(const ushort4*)(zq + col * 40 + wv * 4);
    ushort4 l = *(const ushort4*)(zq + 2560 + col * 40 + wv * 4);
    size_t base = (size_t)(b * 512 + dcPrev + wv * 4) * 1024 + SP0 + col;
    out_z[base         ] = bfu(h.x) + bfu(l.x);
    out_z[base + 1024  ] = bfu(h.y) + bfu(l.y);
    out_z[base + 2048  ] = bfu(h.z) + bfu(l.z);
    out_z[base + 3072  ] = bfu(h.w) + bfu(l.w);
}

static __device__ __forceinline__ void bmerge(float& a1, int& ak, float& a2,
                                              float o1, int ok, float o2) {
    if (o1 < a1)      { a2 = fminf(a1, o2); a1 = o1; ak = ok; }
    else if (o1 > a1) { a2 = fminf(a2, o1); }
    else              { a2 = a1; if (ok < ak) ak = ok; }   // exact tie -> gap 0 (suspect)
}

// ---------------------------------------------------------------------------
// FUSED main v6: 512 blocks x 512 threads, 64 pos/block (256 B write runs),
// 4 waves/SIMD. Wave w: M-half mh=w&1 (2 M-tiles) x N-octet nw=w>>1 (8 N-tiles).
// Single barrier per 32-d chunk: conv(dc)->buf p; mfma+outz(dc-32)<-buf 1-p.
// LDS: patch 12288 | z pairs 2x10240 = 32768 B.
// ---------------------------------------------------------------------------
__global__ __launch_bounds__(512, 4) void k_main(
        const void* __restrict__ x, const float* __restrict__ cWe,
        const float* __restrict__ cbe, const int* __restrict__ nbadp,
        const unsigned short* __restrict__ cbHT, const unsigned short* __restrict__ cbLT,
        const float* __restrict__ cbT, const float* __restrict__ w2,
        float* __restrict__ out_z, float* __restrict__ out_e,
        int* __restrict__ idx, int* __restrict__ scnt, int* __restrict__ spos,
        int skipTail) {
    __shared__ __align__(16) char smc[32768];
    float* patch = (float*)smc;                               // [64][48] fp32
    unsigned short* zb = (unsigned short*)(smc + 12288);      // 2 pairs x 5120 shorts

    const int t = threadIdx.x;
    const int P0 = blockIdx.x * 64;
    const int b = P0 >> 10, SP0 = P0 & 1023;
    const int flag = (*nbadp == 0);
    const int wave = t >> 6, lane = t & 63;
    const int quad = lane >> 4, lcol = lane & 15;
    const int mh = wave & 1, nw = wave >> 1;

    // stage x patches once: 64 pos x 48 taps
    for (int e = t; e < 3072; e += 512) {
        int pid = e / 48, kk = e % 48;
        int c = kk >> 4, r = (kk >> 2) & 3, s = kk & 3;
        int pos = P0 + pid;
        int bb = pos >> 10, sp = pos & 1023, i = sp >> 5, j = sp & 31;
        patch[pid * 48 + kk] = ldin(x, ((bb * 3 + c) * 128 + (i * 4 + r)) * 128 + (j * 4 + s), flag);
    }

    floatx4 acc[2][8];
    #pragma unroll
    for (int mt = 0; mt < 2; ++mt)
        #pragma unroll
        for (int j = 0; j < 8; ++j) acc[mt][j] = (floatx4){0.f, 0.f, 0.f, 0.f};

    __syncthreads();
    conv_step(patch, cWe, cbe, 0, t, zb);              // chunk 0 -> pair 0
    for (int dc = 32; dc < 512; dc += 32) {
        __syncthreads();
        const int p = (dc >> 5) & 1;
        conv_step(patch, cWe, cbe, dc, t, zb + p * 5120);
        mfma_step(zb + (p ^ 1) * 5120, cbHT, cbLT, dc - 32, mh, nw, quad, lcol, flag, acc);
        outz_step(zb + (p ^ 1) * 5120, dc - 32, t, b, SP0, out_z);
    }
    __syncthreads();
    mfma_step(zb + 5120, cbHT, cbLT, 480, mh, nw, quad, lcol, flag, acc);
    outz_step(zb + 5120, 480, t, b, SP0, out_z);

    // ---- epilogue: per-lane best/second over its 8 codes, shuffle over 16 ----
    float s1[2][4], s2[2][4]; int k1[2][4];
    #pragma unroll
    for (int mt = 0; mt < 2; ++mt)
        #pragma unroll
        for (int r = 0; r < 4; ++r) { s1[mt][r] = 1e30f; s2[mt][r] = 1e30f; k1[mt][r] = 511; }
    #pragma unroll
    for (int j = 0; j < 8; ++j) {
        int code = (nw * 8 + j) * 16 + lcol;
        float wk = w2[code];
        #pragma unroll
        for (int mt = 0; mt < 2; ++mt)
            #pragma unroll
            for (int r = 0; r < 4; ++r) {
                float s = wk - 2.f * acc[mt][j][r];
                bmerge(s1[mt][r], k1[mt][r], s2[mt][r], s, code, 1e30f);
            }
    }
    // overlay reduction arrays on patch region (dead after last conv + barrier)
    float* sS1 = (float*)smc;             // [64 pos][4 nw]
    int*   sK1 = (int*)(smc + 1024);
    float* sS2 = (float*)(smc + 2048);
    int*   ii  = (int*)(smc + 3072);      // [64]
    __syncthreads();
    #pragma unroll
    for (int mt = 0; mt < 2; ++mt)
        #pragma unroll
        for (int r = 0; r < 4; ++r) {
            float a1 = s1[mt][r], a2 = s2[mt][r]; int ak = k1[mt][r];
            #pragma unroll
            for (int m = 1; m < 16; m <<= 1) {
                float o1 = __shfl_xor(a1, m);
                float o2 = __shfl_xor(a2, m);
                int   ok = __shfl_xor(ak, m);
                bmerge(a1, ak, a2, o1, ok, o2);
            }
            if (lcol == 0) {
                int pos = (mh * 2 + mt) * 16 + quad * 4 + r;
                sS1[pos * 4 + nw] = a1;
                sK1[pos * 4 + nw] = ak;
                sS2[pos * 4 + nw] = a2;
            }
        }
    __syncthreads();
    if (t < 64) {
        float a1 = sS1[t * 4]; int ak = sK1[t * 4]; float a2 = sS2[t * 4];
        #pragma unroll
        for (int w = 1; w < 4; ++w)
            bmerge(a1, ak, a2, sS1[t * 4 + w], sK1[t * 4 + w], sS2[t * 4 + w]);
        ak &= 511;
        ii[t] = ak;
        idx[P0 + t] = ak;
        if (a2 - a1 < EPS_GAP) {
            int slot = atomicAdd(scnt, 1);
            if (slot < MAXSUS) spos[slot] = P0 + t;
        }
    }
    __syncthreads();

    // ---- fused emb: out_e[b][d][SP0+sp] = cbT[ii[sp]][d] (256 B runs) ----
    const int sp = t & 63, dq = t >> 6;   // 8 strips of 64 d
    const float* row = cbT + (size_t)ii[sp] * 512;
    const size_t obase = ((size_t)b * 512) * 1024 + SP0 + sp;
    for (int d0 = dq * 64; d0 < dq * 64 + 64; d0 += 4) {
        if (skipTail && b == 31 && d0 >= 448) break;
        float4 v = *(const float4*)(row + d0);
        out_e[obase + (size_t)(d0    ) * 1024] = v.x;
        out_e[obase + (size_t)(d0 + 1) * 1024] = v.y;
        out_e[obase + (size_t)(d0 + 2) * 1024] = v.z;
        out_e[obase + (size_t)(d0 + 3) * 1024] = v.w;
    }
}

// ---------------------------------------------------------------------------
// Exact fp64 rescore of suspect positions; patches idx and emb column.
// ---------------------------------------------------------------------------
__global__ __launch_bounds__(256) void k_rescore(
        const float* __restrict__ out_z, const float* __restrict__ cbT,
        const double* __restrict__ w2d, int* __restrict__ idx,
        const int* __restrict__ scnt, const int* __restrict__ spos,
        float* __restrict__ out_e, int skipTail) {
    __shared__ float zsh[512];
    __shared__ float rs[256];
    __shared__ int rk[256];
    __shared__ int bc[2];
    const int t = threadIdx.x;
    int n = *scnt; if (n > MAXSUS) n = MAXSUS;
    for (int s = blockIdx.x; s < n; s += gridDim.x) {
        int p = spos[s] & 32767;
        int b = p >> 10, sp = p & 1023;
        __syncthreads();
        zsh[t]       = out_z[(size_t)(b * 512 + t) * 1024 + sp];
        zsh[t + 256] = out_z[(size_t)(b * 512 + t + 256) * 1024 + sp];
        __syncthreads();
        float bs = 1e30f; int bk = 511;
        for (int cc = 0; cc < 2; ++cc) {
            int k = t + cc * 256;
            double a = 0.0;
            const float* row = cbT + (size_t)k * 512;
            for (int d = 0; d < 512; ++d) a = fma((double)zsh[d], (double)row[d], a);
            float sc = (float)(w2d[k] - 2.0 * a);
            if (sc < bs || (sc == bs && k < bk)) { bs = sc; bk = k; }
        }
        rs[t] = bs; rk[t] = bk;
        __syncthreads();
        for (int str = 128; str > 0; str >>= 1) {
            if (t < str) {
                float so = rs[t + str]; int ko = rk[t + str];
                if (so < rs[t] || (so == rs[t] && ko < rk[t])) { rs[t] = so; rk[t] = ko; }
            }
            __syncthreads();
        }
        if (t == 0) {
            int kstar = rk[0] & 511;
            int old = idx[p] & 511;
            bc[0] = kstar; bc[1] = (kstar != old);
            idx[p] = kstar;
        }
        __syncthreads();
        if (bc[1]) {
            int kk = bc[0];
            for (int d = t; d < 512; d += 256) {
                if (skipTail && b == 31 && d >= 448) continue;
                out_e[(size_t)(b * 512 + d) * 1024 + sp] = cbT[(size_t)kk * 512 + d];
            }
        }
    }
}

// ---------------------------------------------------------------------------
__global__ __launch_bounds__(256) void k_recon(
        const float* __restrict__ U, const int* __restrict__ idx,
        float* __restrict__ out_r) {
    const int pos = blockIdx.x * 256 + threadIdx.x;
    const int id = idx[pos] & 511;
    const int b = pos >> 10, sp = pos & 1023, i = sp >> 5, j = sp & 31;
    const float* u = &U[(size_t)id * 48];
    #pragma unroll
    for (int c = 0; c < 3; ++c)
        #pragma unroll
        for (int uu = 0; uu < 4; ++uu) {
            float4 q = *(const float4*)(&u[c * 16 + uu * 4]);
            float4 o;
            o.x = 1.f / (1.f + __expf(-q.x));
            o.y = 1.f / (1.f + __expf(-q.y));
            o.z = 1.f / (1.f + __expf(-q.z));
            o.w = 1.f / (1.f + __expf(-q.w));
            *(float4*)(&out_r[((size_t)((b * 3 + c) * 128) + (i * 4 + uu)) * 128 + j * 4]) = o;
        }
}

// ---------------------------------------------------------------------------
__global__ __launch_bounds__(1024) void k_fixup(
        const void* __restrict__ cb, const int* __restrict__ nbadp,
        const int* __restrict__ idx, float* __restrict__ out_e) {
    __shared__ int ii[1024];
    __shared__ int sflag;
    const int t = threadIdx.x;
    if (t == 0) sflag = (*nbadp == 0);
    ii[t] = idx[31744 + t] & 511;
    __syncthreads();
    const int flag = sflag;
    for (int e = t; e < 65536; e += 1024) {
        int d = 448 + (e >> 10), sp = e & 1023;
        out_e[((size_t)(31 * 512 + d)) * 1024 + sp] = ldin(cb, (size_t)d * 512 + ii[sp], flag);
    }
}

// ---------------------------------------------------------------------------
extern "C" void kernel_launch(void* const* d_in, const int* in_sizes, int n_in,
                              void* d_out, int out_size, void* d_ws, size_t ws_size,
                              hipStream_t stream) {
    const void* x  = d_in[0];
    const void* We = d_in[1];
    const void* be = d_in[2];
    const void* Wd = d_in[3];
    const void* bd = d_in[4];
    const void* cb = d_in[5];

    float* out   = (float*)d_out;
    float* out_r = out;                       // 1,572,864 fp32 (6.29 MB)
    float* out_z = out + 1572864;             // 16,777,216 fp32
    float* out_e = out + 18350080;            // 16,777,216 fp32

    // Read-mostly tables in out_r (recon overwrites at the very end):
    char* Rb = (char*)out_r;
    float* cbT          = (float*)(Rb);                    // 1,048,576 B
    float* cWe          = (float*)(Rb + 1048576);          //    98,304 B
    float* cbe          = (float*)(Rb + 1146880);          //     2,048 B
    unsigned short* cbHT= (unsigned short*)(Rb + 1148928); //   524,288 B
    unsigned short* cbLT= (unsigned short*)(Rb + 1673216); //   524,288 B

    // Tail scratch: prefer d_ws; else last 256 KB of out_e (fixup required).
    int tailWS = (ws_size >= 262144) ? 1 : 0;
    char* Tbase = tailWS ? (char*)d_ws : ((char*)out_e + 66846720);
    int skipTail = tailWS ? 0 : 1;
    int*    idx  = (int*)   (Tbase);            // 131,072 B
    float*  U    = (float*) (Tbase + 131072);   //  98,304 B
    float*  w2   = (float*) (Tbase + 229376);   //   2,048 B
    double* w2d  = (double*)(Tbase + 231424);   //   4,096 B
    int*    nbad = (int*)   (Tbase + 235520);   //      64 B
    int*    scnt = (int*)   (Tbase + 235584);   //      64 B
    int*    spos = (int*)   (Tbase + 235648);   //  16,384 B

    k_init<<<1, 1, 0, stream>>>(scnt, nbad);
    k_sniff<<<64, 64, 0, stream>>>(cb, nbad);
    k_prep<<<292, 256, 0, stream>>>(cb, We, be, Wd, bd, nbad,
                                    cWe, cbe, cbT, cbHT, cbLT, w2, w2d, U);

    k_main<<<512, 512, 0, stream>>>(x, cWe, cbe, nbad, cbHT, cbLT, cbT, w2,
                                    out_z, out_e, idx, scnt, spos, skipTail);

    k_rescore<<<128, 256, 0, stream>>>(out_z, cbT, w2d, idx, scnt, spos, out_e, skipTail);
    k_recon<<<128, 256, 0, stream>>>(U, idx, out_r);
    if (skipTail)
        k_fixup<<<1, 1024, 0, stream>>>(cb, nbad, idx, out_e);
}

// Round 15
// 365.215 us; speedup vs baseline: 1.2815x; 1.2815x over previous
//
#include <hip/hip_runtime.h>
#include <hip/hip_bf16.h>

// B=32, C=3, H=W=128, D=512, K=512, S=4, NPOS=32768
#define NPOS 32768
#define EPS_GAP 4e-3f
#define MAXSUS 4096

typedef __attribute__((ext_vector_type(8))) short short8;
typedef __attribute__((ext_vector_type(4))) float floatx4;

static __device__ __forceinline__ float bfu(unsigned short h) {
    return __uint_as_float(((unsigned int)h) << 16);
}
static __device__ __forceinline__ unsigned short f2bf(float f) {
    unsigned int u = __float_as_uint(f);
    u = (u + 0x7fffu + ((u >> 16) & 1u)) >> 16;   // RNE
    return (unsigned short)u;
}
static __device__ __forceinline__ float ldin(const void* p, size_t i, int flag) {
    return flag ? bfu(((const unsigned short*)p)[i]) : ((const float*)p)[i];
}

// ---------------------------------------------------------------------------
__global__ void k_init(int* __restrict__ scnt, int* __restrict__ nbad) {
    *scnt = 0; *nbad = 0;
}

// 64 blocks x 64 threads: block = column k; shuffle-reduce sumsq.
__global__ void k_sniff(const void* __restrict__ cb, int* __restrict__ nbad) {
    const unsigned short* u = (const unsigned short*)cb;
    const int k = blockIdx.x, t = threadIdx.x;
    float acc = 0.f;
    #pragma unroll
    for (int i = 0; i < 8; ++i) {
        float v = bfu(u[(size_t)(t + 64 * i) * 512 + k]);
        acc = fmaf(v, v, acc);
    }
    #pragma unroll
    for (int m = 1; m < 64; m <<= 1) acc += __shfl_xor(acc, m);
    if (t == 0 && !(acc >= 100.f && acc <= 2000.f)) atomicAdd(nbad, 1);
}

// ---------------------------------------------------------------------------
// FUSED prep (292 blocks x 256): transpose tiles -> cbT/cbHT/cbLT; canonW;
// w2 (double); udec -> U. (verified in rounds 14)
// ---------------------------------------------------------------------------
__global__ __launch_bounds__(256) void k_prep(
        const void* __restrict__ cb, const void* __restrict__ We,
        const void* __restrict__ be, const void* __restrict__ Wd,
        const void* __restrict__ bd, const int* __restrict__ nbadp,
        float* __restrict__ cWe, float* __restrict__ cbe,
        float* __restrict__ cbT, unsigned short* __restrict__ cbHT,
        unsigned short* __restrict__ cbLT, float* __restrict__ w2,
        double* __restrict__ w2d, float* __restrict__ U) {
    __shared__ float tile[64][65];
    const int flag = (*nbadp == 0);
    const int blk = blockIdx.x, t = threadIdx.x;

    if (blk < 64) {
        const int D0 = (blk & 7) * 64, K0 = (blk >> 3) * 64;
        for (int it = 0; it < 16; ++it) {
            int r = (t >> 6) + 4 * it, c = t & 63;
            tile[r][c] = ldin(cb, (size_t)(D0 + r) * 512 + K0 + c, flag);
        }
        __syncthreads();
        for (int it = 0; it < 16; ++it) {
            int r = (t >> 6) + 4 * it, c = t & 63;
            float v = tile[c][r];
            size_t o = (size_t)(K0 + r) * 512 + D0 + c;
            cbT[o] = v;
            unsigned short h = f2bf(v);
            cbHT[o] = h;
            cbLT[o] = f2bf(v - bfu(h));
        }
    } else if (blk < 162) {
        int e = (blk - 64) * 256 + t;
        if (e < 24576)      cWe[e]         = ldin(We, e, flag);
        else if (e < 25088) cbe[e - 24576] = ldin(be, e - 24576, flag);
    } else if (blk < 164) {
        int k = (blk - 162) * 256 + t;
        double acc = 0.0;
        for (int d = 0; d < 512; ++d) {
            double v = (double)ldin(cb, (size_t)d * 512 + k, flag);
            acc += v * v;
        }
        w2[k] = (float)acc;
        w2d[k] = acc;
    } else {
        const int k = (blk - 164) * 4 + (t >> 6);
        const int lane = t & 63;
        const int j = lane >> 2, dpart = lane & 3;
        const int u = (j >> 2) & 3, v = j & 3;
        int woff[3];
        #pragma unroll
        for (int m = 0; m < 3; ++m) woff[m] = m * 8192 + (3 - u) * 4 + (3 - v);
        float a0 = 0.f, a1 = 0.f, a2 = 0.f;
        for (int i = 0; i < 128; ++i) {
            int d = dpart * 128 + i;
            float cw = ldin(cb, (size_t)d * 512 + k, flag);
            a0 = fmaf(cw, ldin(Wd, woff[0] + d * 16, flag), a0);
            a1 = fmaf(cw, ldin(Wd, woff[1] + d * 16, flag), a1);
            a2 = fmaf(cw, ldin(Wd, woff[2] + d * 16, flag), a2);
        }
        a0 += __shfl_xor(a0, 1); a0 += __shfl_xor(a0, 2);
        a1 += __shfl_xor(a1, 1); a1 += __shfl_xor(a1, 2);
        a2 += __shfl_xor(a2, 1); a2 += __shfl_xor(a2, 2);
        if (dpart == 0) {
            U[k * 48 +  0 + j] = a0 + ldin(bd, 0, flag);
            U[k * 48 + 16 + j] = a1 + ldin(bd, 1, flag);
            U[k * 48 + 32 + j] = a2 + ldin(bd, 2, flag);
        }
    }
}

// ---------------------------------------------------------------------------
// k_conv: encoder only. Block = 64 pos x 64 d, 256 threads, 4096 blocks.
// lane = pos (writes 256 B runs), patch in 48 regs, weights broadcast (LDS).
// ---------------------------------------------------------------------------
__global__ __launch_bounds__(256, 4) void k_conv(
        const void* __restrict__ x, const float* __restrict__ cWe,
        const float* __restrict__ cbe, const int* __restrict__ nbadp,
        float* __restrict__ out_z) {
    __shared__ float patch[64 * 52];   // stride 52 (16B-aligned rows, bank spread)
    __shared__ float wsh[64 * 48];
    __shared__ float bsh[64];
    const int t = threadIdx.x;
    const int spblk = blockIdx.x & 511;
    const int D0 = (blockIdx.x >> 9) * 64;
    const int P0 = spblk * 64;
    const int b = P0 >> 10, SP0 = P0 & 1023;
    const int flag = (*nbadp == 0);

    for (int e = t; e < 3072; e += 256) {
        int pid = e / 48, kk = e % 48;
        int c = kk >> 4, r = (kk >> 2) & 3, s = kk & 3;
        int pos = P0 + pid;
        int bb = pos >> 10, sp = pos & 1023, i = sp >> 5, j = sp & 31;
        patch[pid * 52 + kk] = ldin(x, ((bb * 3 + c) * 128 + (i * 4 + r)) * 128 + (j * 4 + s), flag);
    }
    for (int e = t; e < 3072; e += 256)
        wsh[e] = cWe[(size_t)D0 * 48 + e];
    if (t < 64) bsh[t] = cbe[D0 + t];
    __syncthreads();

    const int pos = t & 63;
    const int dstrip = (t >> 6) * 16;
    float pv[48];
    const float4* pr = (const float4*)(patch + pos * 52);
    #pragma unroll
    for (int q = 0; q < 12; ++q) {
        float4 v = pr[q];
        pv[4*q] = v.x; pv[4*q+1] = v.y; pv[4*q+2] = v.z; pv[4*q+3] = v.w;
    }
    for (int dd = 0; dd < 16; ++dd) {
        int d = dstrip + dd;
        const float4* wr = (const float4*)(wsh + d * 48);
        float acc = bsh[d];
        #pragma unroll
        for (int q = 0; q < 12; ++q) {
            float4 w = wr[q];
            acc = fmaf(pv[4*q],   w.x, acc);
            acc = fmaf(pv[4*q+1], w.y, acc);
            acc = fmaf(pv[4*q+2], w.z, acc);
            acc = fmaf(pv[4*q+3], w.w, acc);
        }
        out_z[(size_t)(b * 512 + D0 + d) * 1024 + SP0 + pos] = fmaxf(acc, 0.f);
    }
}

// ---------------------------------------------------------------------------
// k_gemm: distance argmin only. 1024 blocks x 256 thr, 32 pos/block, 16 waves/CU.
// Per 32-d chunk: load A (out_z), split bf16 H/L -> LDS (double buffer),
// MFMA with B direct from L2. Writes ONLY idx + suspects.
// ---------------------------------------------------------------------------
__global__ __launch_bounds__(256, 4) void k_gemm(
        const float* __restrict__ out_z, const int* __restrict__ nbadp,
        const unsigned short* __restrict__ cbHT, const unsigned short* __restrict__ cbLT,
        const float* __restrict__ w2, int* __restrict__ idx,
        int* __restrict__ scnt, int* __restrict__ spos) {
    __shared__ __align__(16) unsigned short zq[2][2560];  // H [pos*40+d] | L 1280+
    __shared__ float sS1[128];
    __shared__ int   sK1[128];
    __shared__ float sS2[128];
    const int t = threadIdx.x;
    const int P0 = blockIdx.x * 32;
    const int b = P0 >> 10, SP0 = P0 & 1023;
    const int flag = (*nbadp == 0);
    const int wave = t >> 6, lane = t & 63;
    const int quad = lane >> 4, lcol = lane & 15;
    const int r = t >> 3, cg = t & 7;   // A-load roles: 32 d-rows x 8 col-groups

    floatx4 acc[2][8];
    #pragma unroll
    for (int mt = 0; mt < 2; ++mt)
        #pragma unroll
        for (int j = 0; j < 8; ++j) acc[mt][j] = (floatx4){0.f, 0.f, 0.f, 0.f};

    // chunk 0 -> buf 0
    {
        float4 f = *(const float4*)(&out_z[(size_t)(b * 512 + r) * 1024 + SP0 + cg * 4]);
        float ff[4] = {f.x, f.y, f.z, f.w};
        #pragma unroll
        for (int i = 0; i < 4; ++i) {
            unsigned short h = f2bf(ff[i]);
            int pos = cg * 4 + i;
            zq[0][pos * 40 + r] = h;
            zq[0][1280 + pos * 40 + r] = f2bf(ff[i] - bfu(h));
        }
    }
    for (int dc = 32; dc < 512; dc += 32) {
        __syncthreads();
        const int p = (dc >> 5) & 1;
        // load + split chunk dc -> buf p
        {
            float4 f = *(const float4*)(&out_z[(size_t)(b * 512 + dc + r) * 1024 + SP0 + cg * 4]);
            float ff[4] = {f.x, f.y, f.z, f.w};
            #pragma unroll
            for (int i = 0; i < 4; ++i) {
                unsigned short h = f2bf(ff[i]);
                int pos = cg * 4 + i;
                zq[p][pos * 40 + r] = h;
                zq[p][1280 + pos * 40 + r] = f2bf(ff[i] - bfu(h));
            }
        }
        // MFMA chunk dc-32 from buf p^1
        {
            const unsigned short* zb = zq[p ^ 1];
            const int dcPrev = dc - 32;
            short8 aH[2], aL[2];
            #pragma unroll
            for (int mt = 0; mt < 2; ++mt) {
                int pos = mt * 16 + lcol;
                aH[mt] = *(const short8*)(zb + pos * 40 + quad * 8);
                aL[mt] = *(const short8*)(zb + 1280 + pos * 40 + quad * 8);
            }
            #pragma unroll
            for (int j = 0; j < 8; ++j) {
                int code = (wave * 8 + j) * 16 + lcol;
                short8 bH = *(const short8*)(cbHT + (size_t)code * 512 + dcPrev + quad * 8);
                #pragma unroll
                for (int mt = 0; mt < 2; ++mt) {
                    acc[mt][j] = __builtin_amdgcn_mfma_f32_16x16x32_bf16(aH[mt], bH, acc[mt][j], 0, 0, 0);
                    acc[mt][j] = __builtin_amdgcn_mfma_f32_16x16x32_bf16(aL[mt], bH, acc[mt][j], 0, 0, 0);
                }
            }
            if (!flag) {
                #pragma unroll
                for (int j = 0; j < 8; ++j) {
                    int code = (wave * 8 + j) * 16 + lcol;
                    short8 bL = *(const short8*)(cbLT + (size_t)code * 512 + dcPrev + quad * 8);
                    #pragma unroll
                    for (int mt = 0; mt < 2; ++mt)
                        acc[mt][j] = __builtin_amdgcn_mfma_f32_16x16x32_bf16(aH[mt], bL, acc[mt][j], 0, 0, 0);
                }
            }
        }
    }
    __syncthreads();
    // last chunk (dc=480) lives in buf 1
    {
        const unsigned short* zb = zq[1];
        short8 aH[2], aL[2];
        #pragma unroll
        for (int mt = 0; mt < 2; ++mt) {
            int pos = mt * 16 + lcol;
            aH[mt] = *(const short8*)(zb + pos * 40 + quad * 8);
            aL[mt] = *(const short8*)(zb + 1280 + pos * 40 + quad * 8);
        }
        #pragma unroll
        for (int j = 0; j < 8; ++j) {
            int code = (wave * 8 + j) * 16 + lcol;
            short8 bH = *(const short8*)(cbHT + (size_t)code * 512 + 480 + quad * 8);
            #pragma unroll
            for (int mt = 0; mt < 2; ++mt) {
                acc[mt][j] = __builtin_amdgcn_mfma_f32_16x16x32_bf16(aH[mt], bH, acc[mt][j], 0, 0, 0);
                acc[mt][j] = __builtin_amdgcn_mfma_f32_16x16x32_bf16(aL[mt], bH, acc[mt][j], 0, 0, 0);
            }
        }
        if (!flag) {
            #pragma unroll
            for (int j = 0; j < 8; ++j) {
                int code = (wave * 8 + j) * 16 + lcol;
                short8 bL = *(const short8*)(cbLT + (size_t)code * 512 + 480 + quad * 8);
                #pragma unroll
                for (int mt = 0; mt < 2; ++mt)
                    acc[mt][j] = __builtin_amdgcn_mfma_f32_16x16x32_bf16(aH[mt], bL, acc[mt][j], 0, 0, 0);
            }
        }
    }

    // ---- epilogue: per-lane best/second, shuffle over 16, cross-wave via LDS ----
    float s1[2][4], s2[2][4]; int k1[2][4];
    #pragma unroll
    for (int mt = 0; mt < 2; ++mt)
        #pragma unroll
        for (int rr = 0; rr < 4; ++rr) { s1[mt][rr] = 1e30f; s2[mt][rr] = 1e30f; k1[mt][rr] = 511; }
    #pragma unroll
    for (int j = 0; j < 8; ++j) {
        int code = (wave * 8 + j) * 16 + lcol;
        float wk = w2[code];
        #pragma unroll
        for (int mt = 0; mt < 2; ++mt)
            #pragma unroll
            for (int rr = 0; rr < 4; ++rr) {
                float s = wk - 2.f * acc[mt][j][rr];
                if (s < s1[mt][rr])      { s2[mt][rr] = s1[mt][rr]; s1[mt][rr] = s; k1[mt][rr] = code; }
                else if (s > s1[mt][rr]) { s2[mt][rr] = fminf(s2[mt][rr], s); }
                else                     { s2[mt][rr] = s1[mt][rr]; if (code < k1[mt][rr]) k1[mt][rr] = code; }
            }
    }
    #pragma unroll
    for (int mt = 0; mt < 2; ++mt)
        #pragma unroll
        for (int rr = 0; rr < 4; ++rr) {
            float a1 = s1[mt][rr], a2 = s2[mt][rr]; int ak = k1[mt][rr];
            #pragma unroll
            for (int m = 1; m < 16; m <<= 1) {
                float o1 = __shfl_xor(a1, m);
                float o2 = __shfl_xor(a2, m);
                int   ok = __shfl_xor(ak, m);
                if (o1 < a1)      { a2 = fminf(a1, o2); a1 = o1; ak = ok; }
                else if (o1 > a1) { a2 = fminf(a2, o1); }
                else              { a2 = a1; if (ok < ak) ak = ok; }
            }
            if (lcol == 0) {
                int pos = mt * 16 + quad * 4 + rr;
                sS1[pos * 4 + wave] = a1;
                sK1[pos * 4 + wave] = ak;
                sS2[pos * 4 + wave] = a2;
            }
        }
    __syncthreads();
    if (t < 32) {
        float a1 = sS1[t * 4]; int ak = sK1[t * 4]; float a2 = sS2[t * 4];
        #pragma unroll
        for (int w = 1; w < 4; ++w) {
            float o1 = sS1[t * 4 + w], o2 = sS2[t * 4 + w]; int ok = sK1[t * 4 + w];
            if (o1 < a1)      { a2 = fminf(a1, o2); a1 = o1; ak = ok; }
            else if (o1 > a1) { a2 = fminf(a2, o1); }
            else              { a2 = a1; if (ok < ak) ak = ok; }
        }
        ak &= 511;
        idx[P0 + t] = ak;
        if (a2 - a1 < EPS_GAP) {
            int slot = atomicAdd(scnt, 1);
            if (slot < MAXSUS) spos[slot] = P0 + t;
        }
    }
}

// ---------------------------------------------------------------------------
// k_emb: out_e[b][d][sp] = cbT[idx[pos]][d]. 512 blocks, 64-sp slices,
// 256 B write runs. Skips scratch tail (b==31 && d>=448).
// ---------------------------------------------------------------------------
__global__ __launch_bounds__(256) void k_emb(
        const float* __restrict__ cbT, const int* __restrict__ idx,
        float* __restrict__ out_e, int skipTail) {
    __shared__ int ii[64];
    const int t = threadIdx.x;
    const int b = blockIdx.x >> 4;
    const int SP0 = (blockIdx.x & 15) * 64;
    if (t < 64) ii[t] = idx[b * 1024 + SP0 + t] & 511;
    __syncthreads();
    const int sp = t & 63, dq = t >> 6;
    const float* row = cbT + (size_t)ii[sp] * 512;
    const size_t obase = ((size_t)b * 512) * 1024 + SP0 + sp;
    for (int d0 = dq * 128; d0 < dq * 128 + 128; d0 += 4) {
        if (skipTail && b == 31 && d0 >= 448) break;
        float4 v = *(const float4*)(row + d0);
        out_e[obase + (size_t)(d0    ) * 1024] = v.x;
        out_e[obase + (size_t)(d0 + 1) * 1024] = v.y;
        out_e[obase + (size_t)(d0 + 2) * 1024] = v.z;
        out_e[obase + (size_t)(d0 + 3) * 1024] = v.w;
    }
}

// ---------------------------------------------------------------------------
// Exact fp64 rescore of suspects; patches idx and emb column. Runs AFTER k_emb.
// ---------------------------------------------------------------------------
__global__ __launch_bounds__(256) void k_rescore(
        const float* __restrict__ out_z, const float* __restrict__ cbT,
        const double* __restrict__ w2d, int* __restrict__ idx,
        const int* __restrict__ scnt, const int* __restrict__ spos,
        float* __restrict__ out_e, int skipTail) {
    __shared__ float zsh[512];
    __shared__ float rs[256];
    __shared__ int rk[256];
    __shared__ int bc[2];
    const int t = threadIdx.x;
    int n = *scnt; if (n > MAXSUS) n = MAXSUS;
    for (int s = blockIdx.x; s < n; s += gridDim.x) {
        int p = spos[s] & 32767;
        int b = p >> 10, sp = p & 1023;
        __syncthreads();
        zsh[t]       = out_z[(size_t)(b * 512 + t) * 1024 + sp];
        zsh[t + 256] = out_z[(size_t)(b * 512 + t + 256) * 1024 + sp];
        __syncthreads();
        float bs = 1e30f; int bk = 511;
        for (int cc = 0; cc < 2; ++cc) {
            int k = t + cc * 256;
            double a = 0.0;
            const float* row = cbT + (size_t)k * 512;
            for (int d = 0; d < 512; ++d) a = fma((double)zsh[d], (double)row[d], a);
            float sc = (float)(w2d[k] - 2.0 * a);
            if (sc < bs || (sc == bs && k < bk)) { bs = sc; bk = k; }
        }
        rs[t] = bs; rk[t] = bk;
        __syncthreads();
        for (int str = 128; str > 0; str >>= 1) {
            if (t < str) {
                float so = rs[t + str]; int ko = rk[t + str];
                if (so < rs[t] || (so == rs[t] && ko < rk[t])) { rs[t] = so; rk[t] = ko; }
            }
            __syncthreads();
        }
        if (t == 0) {
            int kstar = rk[0] & 511;
            int old = idx[p] & 511;
            bc[0] = kstar; bc[1] = (kstar != old);
            idx[p] = kstar;
        }
        __syncthreads();
        if (bc[1]) {
            int kk = bc[0];
            for (int d = t; d < 512; d += 256) {
                if (skipTail && b == 31 && d >= 448) continue;
                out_e[(size_t)(b * 512 + d) * 1024 + sp] = cbT[(size_t)kk * 512 + d];
            }
        }
    }
}

// ---------------------------------------------------------------------------
__global__ __launch_bounds__(256) void k_recon(
        const float* __restrict__ U, const int* __restrict__ idx,
        float* __restrict__ out_r) {
    const int pos = blockIdx.x * 256 + threadIdx.x;
    const int id = idx[pos] & 511;
    const int b = pos >> 10, sp = pos & 1023, i = sp >> 5, j = sp & 31;
    const float* u = &U[(size_t)id * 48];
    #pragma unroll
    for (int c = 0; c < 3; ++c)
        #pragma unroll
        for (int uu = 0; uu < 4; ++uu) {
            float4 q = *(const float4*)(&u[c * 16 + uu * 4]);
            float4 o;
            o.x = 1.f / (1.f + __expf(-q.x));
            o.y = 1.f / (1.f + __expf(-q.y));
            o.z = 1.f / (1.f + __expf(-q.z));
            o.w = 1.f / (1.f + __expf(-q.w));
            *(float4*)(&out_r[((size_t)((b * 3 + c) * 128) + (i * 4 + uu)) * 128 + j * 4]) = o;
        }
}

// ---------------------------------------------------------------------------
__global__ __launch_bounds__(1024) void k_fixup(
        const void* __restrict__ cb, const int* __restrict__ nbadp,
        const int* __restrict__ idx, float* __restrict__ out_e) {
    __shared__ int ii[1024];
    __shared__ int sflag;
    const int t = threadIdx.x;
    if (t == 0) sflag = (*nbadp == 0);
    ii[t] = idx[31744 + t] & 511;
    __syncthreads();
    const int flag = sflag;
    for (int e = t; e < 65536; e += 1024) {
        int d = 448 + (e >> 10), sp = e & 1023;
        out_e[((size_t)(31 * 512 + d)) * 1024 + sp] = ldin(cb, (size_t)d * 512 + ii[sp], flag);
    }
}

// ---------------------------------------------------------------------------
extern "C" void kernel_launch(void* const* d_in, const int* in_sizes, int n_in,
                              void* d_out, int out_size, void* d_ws, size_t ws_size,
                              hipStream_t stream) {
    const void* x  = d_in[0];
    const void* We = d_in[1];
    const void* be = d_in[2];
    const void* Wd = d_in[3];
    const void* bd = d_in[4];
    const void* cb = d_in[5];

    float* out   = (float*)d_out;
    float* out_r = out;                       // 1,572,864 fp32 (6.29 MB)
    float* out_z = out + 1572864;             // 16,777,216 fp32
    float* out_e = out + 18350080;            // 16,777,216 fp32

    // Read-mostly tables in out_r (recon overwrites at the very end):
    char* Rb = (char*)out_r;
    float* cbT          = (float*)(Rb);                    // 1,048,576 B
    float* cWe          = (float*)(Rb + 1048576);          //    98,304 B
    float* cbe          = (float*)(Rb + 1146880);          //     2,048 B
    unsigned short* cbHT= (unsigned short*)(Rb + 1148928); //   524,288 B
    unsigned short* cbLT= (unsigned short*)(Rb + 1673216); //   524,288 B

    // Tail scratch: prefer d_ws; else last 256 KB of out_e (fixup required).
    int tailWS = (ws_size >= 262144) ? 1 : 0;
    char* Tbase = tailWS ? (char*)d_ws : ((char*)out_e + 66846720);
    int skipTail = tailWS ? 0 : 1;
    int*    idx  = (int*)   (Tbase);            // 131,072 B
    float*  U    = (float*) (Tbase + 131072);   //  98,304 B
    float*  w2   = (float*) (Tbase + 229376);   //   2,048 B
    double* w2d  = (double*)(Tbase + 231424);   //   4,096 B
    int*    nbad = (int*)   (Tbase + 235520);   //      64 B
    int*    scnt = (int*)   (Tbase + 235584);   //      64 B
    int*    spos = (int*)   (Tbase + 235648);   //  16,384 B

    k_init<<<1, 1, 0, stream>>>(scnt, nbad);
    k_sniff<<<64, 64, 0, stream>>>(cb, nbad);
    k_prep<<<292, 256, 0, stream>>>(cb, We, be, Wd, bd, nbad,
                                    cWe, cbe, cbT, cbHT, cbLT, w2, w2d, U);

    k_conv<<<4096, 256, 0, stream>>>(x, cWe, cbe, nbad, out_z);
    k_gemm<<<1024, 256, 0, stream>>>(out_z, nbad, cbHT, cbLT, w2, idx, scnt, spos);
    k_emb<<<512, 256, 0, stream>>>(cbT, idx, out_e, skipTail);

    k_rescore<<<128, 256, 0, stream>>>(out_z, cbT, w2d, idx, scnt, spos, out_e, skipTail);
    k_recon<<<128, 256, 0, stream>>>(U, idx, out_r);
    if (skipTail)
        k_fixup<<<1, 1024, 0, stream>>>(cb, nbad, idx, out_e);
}